// Round 1
// baseline (974.042 us; speedup 1.0000x reference)
//
#include <hip/hip_runtime.h>

// EdgeGATConv on MI355X.
// Decomposition:
//   k_node_proj : src = x@W_src+b, dst = x@W_dst+b; store src_proj [N,64];
//                 alpha_sn[n,h] = sum_c src*att_src, alpha_dn likewise (dst proj never stored)
//   k_prep      : V[k,h] = sum_c W_edge[k,h*16+c]*att_edge[h,c]  (16x4) + reduced bias
//   k_edge_alpha: per edge: alpha = leaky(alpha_sn[src]+alpha_dn[dst]+ea@V+be);
//                 w = exp(alpha) (no max-subtract needed; |alpha| small);
//                 store w [E,4]; atomicAdd denominator s_sum[dst,h]
//   k_scatter   : wave per edge: out[dst,:] += w[e,h]*src_proj[src,:]  (64 atomics/edge)
//   k_norm      : out[n,h,c] /= (s_sum[n,h] + 1e-16)

#define N_NODES 100000
#define N_EDGES 1600000

__global__ __launch_bounds__(256) void k_node_proj(
    const float* __restrict__ x, const float* __restrict__ Wsrc,
    const float* __restrict__ bsrc, const float* __restrict__ Wdst,
    const float* __restrict__ bdst, const float* __restrict__ att_src,
    const float* __restrict__ att_dst, float* __restrict__ src_proj,
    float* __restrict__ alpha_sn, float* __restrict__ alpha_dn)
{
    const int col  = threadIdx.x & 63;
    // readfirstlane: force wave-uniform node base so x loads scalarize (s_load / merged)
    const int quad = __builtin_amdgcn_readfirstlane(threadIdx.x >> 6);
    const int nbase = blockIdx.x * 32 + quad * 8;

    float accS[8], accD[8];
#pragma unroll
    for (int i = 0; i < 8; ++i) { accS[i] = 0.f; accD[i] = 0.f; }

    for (int k4 = 0; k4 < 128; k4 += 4) {
        float4 xv[8];
#pragma unroll
        for (int i = 0; i < 8; ++i)
            xv[i] = *(const float4*)(x + (size_t)(nbase + i) * 128 + k4);
#pragma unroll
        for (int kk = 0; kk < 4; ++kk) {
            float wsv = Wsrc[(k4 + kk) * 64 + col];
            float wdv = Wdst[(k4 + kk) * 64 + col];
#pragma unroll
            for (int i = 0; i < 8; ++i) {
                float xvk = ((const float*)&xv[i])[kk];
                accS[i] = fmaf(xvk, wsv, accS[i]);
                accD[i] = fmaf(xvk, wdv, accD[i]);
            }
        }
    }

    const float bs = bsrc[col], bd = bdst[col];
    const float as_ = att_src[col], ad_ = att_dst[col];
    const int h = col >> 4;
#pragma unroll
    for (int i = 0; i < 8; ++i) {
        const int n = nbase + i;
        float vS = accS[i] + bs;
        float vD = accD[i] + bd;
        src_proj[(size_t)n * 64 + col] = vS;
        float t1 = vS * as_;
        float t2 = vD * ad_;
#pragma unroll
        for (int off = 8; off >= 1; off >>= 1) {
            t1 += __shfl_xor(t1, off, 16);
            t2 += __shfl_xor(t2, off, 16);
        }
        if ((col & 15) == 0) {
            alpha_sn[n * 4 + h] = t1;
            alpha_dn[n * 4 + h] = t2;
        }
    }
}

// V[k*4+h] = sum_c W_edge[k*64 + h*16 + c] * att_edge[h*16+c];  V[64+h] = reduced bias
__global__ void k_prep(const float* __restrict__ We, const float* __restrict__ be,
                       const float* __restrict__ att_e, float* __restrict__ V)
{
    const int t = threadIdx.x;            // 64 threads
    const int k = t >> 2, h = t & 3;
    float acc = 0.f;
    for (int c = 0; c < 16; ++c)
        acc += We[k * 64 + h * 16 + c] * att_e[h * 16 + c];
    V[k * 4 + h] = acc;
    if (t < 4) {
        float b = 0.f;
        for (int c = 0; c < 16; ++c)
            b += be[t * 16 + c] * att_e[t * 16 + c];
        V[64 + t] = b;
    }
}

__global__ __launch_bounds__(256) void k_edge_alpha(
    const int* __restrict__ ei, const float* __restrict__ ea,
    const float* __restrict__ V, const float* __restrict__ alpha_sn,
    const float* __restrict__ alpha_dn, float* __restrict__ w,
    float* __restrict__ s_sum)
{
    __shared__ float Vs[68];
    if (threadIdx.x < 68) Vs[threadIdx.x] = V[threadIdx.x];
    __syncthreads();

    const int e = blockIdx.x * 256 + threadIdx.x;
    if (e >= N_EDGES) return;
    const int src = ei[e];
    const int dst = ei[N_EDGES + e];

    const float4* ea4 = (const float4*)(ea + (size_t)e * 16);
    float ek[16];
    {
        float4 c0 = ea4[0], c1 = ea4[1], c2 = ea4[2], c3 = ea4[3];
        ek[0]=c0.x; ek[1]=c0.y; ek[2]=c0.z; ek[3]=c0.w;
        ek[4]=c1.x; ek[5]=c1.y; ek[6]=c1.z; ek[7]=c1.w;
        ek[8]=c2.x; ek[9]=c2.y; ek[10]=c2.z; ek[11]=c2.w;
        ek[12]=c3.x; ek[13]=c3.y; ek[14]=c3.z; ek[15]=c3.w;
    }
    float ae[4] = {Vs[64], Vs[65], Vs[66], Vs[67]};
#pragma unroll
    for (int k = 0; k < 16; ++k) {
#pragma unroll
        for (int h = 0; h < 4; ++h)
            ae[h] = fmaf(ek[k], Vs[k * 4 + h], ae[h]);
    }

    const float4 asn = *(const float4*)(alpha_sn + (size_t)src * 4);
    const float4 adn = *(const float4*)(alpha_dn + (size_t)dst * 4);
    float a0 = ae[0] + asn.x + adn.x;
    float a1 = ae[1] + asn.y + adn.y;
    float a2 = ae[2] + asn.z + adn.z;
    float a3 = ae[3] + asn.w + adn.w;
    a0 = (a0 >= 0.f) ? a0 : 0.2f * a0;
    a1 = (a1 >= 0.f) ? a1 : 0.2f * a1;
    a2 = (a2 >= 0.f) ? a2 : 0.2f * a2;
    a3 = (a3 >= 0.f) ? a3 : 0.2f * a3;
    float w0 = __expf(a0), w1 = __expf(a1), w2 = __expf(a2), w3 = __expf(a3);

    *(float4*)(w + (size_t)e * 4) = make_float4(w0, w1, w2, w3);
    atomicAdd(&s_sum[dst * 4 + 0], w0);
    atomicAdd(&s_sum[dst * 4 + 1], w1);
    atomicAdd(&s_sum[dst * 4 + 2], w2);
    atomicAdd(&s_sum[dst * 4 + 3], w3);
}

__global__ __launch_bounds__(256) void k_scatter(
    const int* __restrict__ ei, const float* __restrict__ w,
    const float* __restrict__ src_proj, float* __restrict__ out)
{
    const int lane = threadIdx.x & 63;
    const int wave = (blockIdx.x * 256 + threadIdx.x) >> 6;
    const int nwaves = (gridDim.x * 256) >> 6;
    const int h = lane >> 4;
    for (int e = wave; e < N_EDGES; e += nwaves) {
        const int src = ei[e];
        const int dst = ei[N_EDGES + e];
        const float wv = w[(size_t)e * 4 + h];
        const float v  = src_proj[(size_t)src * 64 + lane];
        atomicAdd(&out[(size_t)dst * 64 + lane], wv * v);
    }
}

__global__ __launch_bounds__(256) void k_norm(float* __restrict__ out,
                                              const float* __restrict__ s_sum)
{
    const int i = blockIdx.x * 256 + threadIdx.x;
    if (i >= N_NODES * 64) return;
    const int n = i >> 6;
    const int h = (i >> 4) & 3;
    out[i] = out[i] / (s_sum[n * 4 + h] + 1e-16f);
}

extern "C" void kernel_launch(void* const* d_in, const int* in_sizes, int n_in,
                              void* d_out, int out_size, void* d_ws, size_t ws_size,
                              hipStream_t stream) {
    const float* x     = (const float*)d_in[0];
    const int*   ei    = (const int*)d_in[1];
    const float* ea    = (const float*)d_in[2];
    const float* Wsrc  = (const float*)d_in[3];
    const float* bsrc  = (const float*)d_in[4];
    const float* Wdst  = (const float*)d_in[5];
    const float* bdst  = (const float*)d_in[6];
    const float* We    = (const float*)d_in[7];
    const float* be    = (const float*)d_in[8];
    const float* att_s = (const float*)d_in[9];
    const float* att_d = (const float*)d_in[10];
    const float* att_e = (const float*)d_in[11];
    float* out = (float*)d_out;

    // workspace layout (floats): total 14,000,068 floats = 56 MB
    float* wsf      = (float*)d_ws;
    float* src_proj = wsf;                                   // N*64
    float* alpha_sn = src_proj + (size_t)N_NODES * 64;       // N*4
    float* alpha_dn = alpha_sn + (size_t)N_NODES * 4;        // N*4
    float* s_sum    = alpha_dn + (size_t)N_NODES * 4;        // N*4
    float* wexp     = s_sum    + (size_t)N_NODES * 4;        // E*4
    float* V        = wexp     + (size_t)N_EDGES * 4;        // 68

    hipMemsetAsync(out,   0, (size_t)N_NODES * 64 * sizeof(float), stream);
    hipMemsetAsync(s_sum, 0, (size_t)N_NODES * 4 * sizeof(float), stream);

    k_node_proj<<<N_NODES / 32, 256, 0, stream>>>(x, Wsrc, bsrc, Wdst, bdst,
                                                  att_s, att_d, src_proj,
                                                  alpha_sn, alpha_dn);
    k_prep<<<1, 64, 0, stream>>>(We, be, att_e, V);
    k_edge_alpha<<<(N_EDGES + 255) / 256, 256, 0, stream>>>(ei, ea, V, alpha_sn,
                                                            alpha_dn, wexp, s_sum);
    k_scatter<<<2048, 256, 0, stream>>>(ei, wexp, src_proj, out);
    k_norm<<<(N_NODES * 64) / 256, 256, 0, stream>>>(out, s_sum);
}

// Round 2
// 804.492 us; speedup vs baseline: 1.2108x; 1.2108x over previous
//
#include <hip/hip_runtime.h>

// EdgeGATConv on MI355X — R2: CSR-by-dst gather instead of atomic scatter.
// Pipeline:
//   k_node_proj : src_proj = x@W_src+b (stored); alpha_sn/alpha_dn = attention dots
//   k_prep      : V[k,h] = reduce(W_edge, att_edge), + reduced bias
//   k_hist      : cnt[dst]++
//   k_scan      : exclusive scan cnt -> row_start, cursor   (single block)
//   k_fill      : per edge: w = exp(leaky(asn[src]+adn[dst]+ea@V+be));
//                 slot = cursor[dst]++; rec_src[slot]=src; rec_w[slot]=w (float4)
//   k_gather    : wave per node: acc[l] += w[h]*src_proj[src][l]; denom += w[h];
//                 out[n][l] = acc/(denom+1e-16)   -- zero atomics, one store

#define N_NODES 100000
#define N_EDGES 1600000
#define SCAN_T 1024
#define SCAN_CHUNK 98   // ceil(100000/1024)

__global__ __launch_bounds__(256) void k_node_proj(
    const float* __restrict__ x, const float* __restrict__ Wsrc,
    const float* __restrict__ bsrc, const float* __restrict__ Wdst,
    const float* __restrict__ bdst, const float* __restrict__ att_src,
    const float* __restrict__ att_dst, float* __restrict__ src_proj,
    float* __restrict__ alpha_sn, float* __restrict__ alpha_dn)
{
    __shared__ float xs[32 * 128];              // 16 KB: 32 node rows
    const int tid = threadIdx.x;
    const int nbase = blockIdx.x * 32;

    const float4* xsrc = (const float4*)(x + (size_t)nbase * 128);
    float4* xd = (float4*)xs;
#pragma unroll
    for (int i = 0; i < 4; ++i)
        xd[tid + i * 256] = xsrc[tid + i * 256];
    __syncthreads();

    const int col = tid & 63;
    const int g = tid >> 6;                     // wave id 0..3, nodes g*8..g*8+7

    float accS[8], accD[8];
#pragma unroll
    for (int i = 0; i < 8; ++i) { accS[i] = 0.f; accD[i] = 0.f; }

    for (int k4 = 0; k4 < 128; k4 += 4) {
        float4 xv[8];
#pragma unroll
        for (int i = 0; i < 8; ++i)
            xv[i] = *(const float4*)&xs[(g * 8 + i) * 128 + k4];
#pragma unroll
        for (int kk = 0; kk < 4; ++kk) {
            float wsv = Wsrc[(k4 + kk) * 64 + col];
            float wdv = Wdst[(k4 + kk) * 64 + col];
#pragma unroll
            for (int i = 0; i < 8; ++i) {
                float xvk = ((const float*)&xv[i])[kk];
                accS[i] = fmaf(xvk, wsv, accS[i]);
                accD[i] = fmaf(xvk, wdv, accD[i]);
            }
        }
    }

    const float bs = bsrc[col], bd = bdst[col];
    const float as_ = att_src[col], ad_ = att_dst[col];
    const int h = col >> 4;
#pragma unroll
    for (int i = 0; i < 8; ++i) {
        const int n = nbase + g * 8 + i;
        float vS = accS[i] + bs;
        float vD = accD[i] + bd;
        src_proj[(size_t)n * 64 + col] = vS;
        float t1 = vS * as_;
        float t2 = vD * ad_;
#pragma unroll
        for (int off = 8; off >= 1; off >>= 1) {
            t1 += __shfl_xor(t1, off, 16);
            t2 += __shfl_xor(t2, off, 16);
        }
        if ((col & 15) == 0) {
            alpha_sn[n * 4 + h] = t1;
            alpha_dn[n * 4 + h] = t2;
        }
    }
}

__global__ void k_prep(const float* __restrict__ We, const float* __restrict__ be,
                       const float* __restrict__ att_e, float* __restrict__ V)
{
    const int t = threadIdx.x;            // 64 threads
    const int k = t >> 2, h = t & 3;
    float acc = 0.f;
    for (int c = 0; c < 16; ++c)
        acc += We[k * 64 + h * 16 + c] * att_e[h * 16 + c];
    V[k * 4 + h] = acc;
    if (t < 4) {
        float b = 0.f;
        for (int c = 0; c < 16; ++c)
            b += be[t * 16 + c] * att_e[t * 16 + c];
        V[64 + t] = b;
    }
}

__global__ __launch_bounds__(256) void k_hist(const int* __restrict__ ei,
                                               int* __restrict__ cnt)
{
    const int e = blockIdx.x * 256 + threadIdx.x;
    if (e >= N_EDGES) return;
    atomicAdd(&cnt[ei[N_EDGES + e]], 1);
}

__global__ __launch_bounds__(SCAN_T) void k_scan(const int* __restrict__ cnt,
                                                  int* __restrict__ row_start,
                                                  int* __restrict__ cursor)
{
    __shared__ int sums[SCAN_T];
    const int t = threadIdx.x;
    const int begin = t * SCAN_CHUNK;
    const int end = min(begin + SCAN_CHUNK, N_NODES);
    int s = 0;
    for (int i = begin; i < end; ++i) s += cnt[i];
    sums[t] = s;
    __syncthreads();
    for (int off = 1; off < SCAN_T; off <<= 1) {
        int v = (t >= off) ? sums[t - off] : 0;
        __syncthreads();
        sums[t] += v;
        __syncthreads();
    }
    int run = (t == 0) ? 0 : sums[t - 1];
    for (int i = begin; i < end; ++i) {
        int c = cnt[i];
        row_start[i] = run;
        cursor[i] = run;
        run += c;
    }
    if (begin < N_NODES && end == N_NODES)
        row_start[N_NODES] = run;
}

__global__ __launch_bounds__(256) void k_fill(
    const int* __restrict__ ei, const float* __restrict__ ea,
    const float* __restrict__ V, const float* __restrict__ alpha_sn,
    const float* __restrict__ alpha_dn, int* __restrict__ cursor,
    int* __restrict__ rec_src, float4* __restrict__ rec_w)
{
    __shared__ float Vs[68];
    if (threadIdx.x < 68) Vs[threadIdx.x] = V[threadIdx.x];
    __syncthreads();

    const int e = blockIdx.x * 256 + threadIdx.x;
    if (e >= N_EDGES) return;
    const int src = ei[e];
    const int dst = ei[N_EDGES + e];

    const float4* ea4 = (const float4*)(ea + (size_t)e * 16);
    float ek[16];
    {
        float4 c0 = ea4[0], c1 = ea4[1], c2 = ea4[2], c3 = ea4[3];
        ek[0]=c0.x; ek[1]=c0.y; ek[2]=c0.z; ek[3]=c0.w;
        ek[4]=c1.x; ek[5]=c1.y; ek[6]=c1.z; ek[7]=c1.w;
        ek[8]=c2.x; ek[9]=c2.y; ek[10]=c2.z; ek[11]=c2.w;
        ek[12]=c3.x; ek[13]=c3.y; ek[14]=c3.z; ek[15]=c3.w;
    }
    float a[4] = {Vs[64], Vs[65], Vs[66], Vs[67]};
#pragma unroll
    for (int k = 0; k < 16; ++k) {
#pragma unroll
        for (int h = 0; h < 4; ++h)
            a[h] = fmaf(ek[k], Vs[k * 4 + h], a[h]);
    }

    const float4 asn = *(const float4*)(alpha_sn + (size_t)src * 4);
    const float4 adn = *(const float4*)(alpha_dn + (size_t)dst * 4);
    float a0 = a[0] + asn.x + adn.x;
    float a1 = a[1] + asn.y + adn.y;
    float a2 = a[2] + asn.z + adn.z;
    float a3 = a[3] + asn.w + adn.w;
    a0 = (a0 >= 0.f) ? a0 : 0.2f * a0;
    a1 = (a1 >= 0.f) ? a1 : 0.2f * a1;
    a2 = (a2 >= 0.f) ? a2 : 0.2f * a2;
    a3 = (a3 >= 0.f) ? a3 : 0.2f * a3;

    const int slot = atomicAdd(&cursor[dst], 1);
    rec_src[slot] = src;
    rec_w[slot] = make_float4(__expf(a0), __expf(a1), __expf(a2), __expf(a3));
}

__global__ __launch_bounds__(256) void k_gather(
    const int* __restrict__ row_start, const int* __restrict__ rec_src,
    const float* __restrict__ rec_w, const float* __restrict__ src_proj,
    float* __restrict__ out)
{
    const int lane = threadIdx.x & 63;
    const int node = (blockIdx.x * 256 + threadIdx.x) >> 6;
    const int h = lane >> 4;
    const int base = row_start[node];
    const int end = row_start[node + 1];

    float acc = 0.f, denom = 0.f;
    for (int j = base; j < end; ++j) {
        const int src = rec_src[j];                       // wave-uniform load
        const float wv = rec_w[(size_t)j * 4 + h];        // 4 distinct addrs
        const float v = src_proj[(size_t)src * 64 + lane];// 256B coalesced
        denom += wv;
        acc = fmaf(wv, v, acc);
    }
    out[(size_t)node * 64 + lane] = acc / (denom + 1e-16f);
}

extern "C" void kernel_launch(void* const* d_in, const int* in_sizes, int n_in,
                              void* d_out, int out_size, void* d_ws, size_t ws_size,
                              hipStream_t stream) {
    const float* x     = (const float*)d_in[0];
    const int*   ei    = (const int*)d_in[1];
    const float* ea    = (const float*)d_in[2];
    const float* Wsrc  = (const float*)d_in[3];
    const float* bsrc  = (const float*)d_in[4];
    const float* Wdst  = (const float*)d_in[5];
    const float* bdst  = (const float*)d_in[6];
    const float* We    = (const float*)d_in[7];
    const float* be    = (const float*)d_in[8];
    const float* att_s = (const float*)d_in[9];
    const float* att_d = (const float*)d_in[10];
    const float* att_e = (const float*)d_in[11];
    float* out = (float*)d_out;

    // workspace layout (4-byte units); all float4 arrays 16B-aligned
    float* wsf      = (float*)d_ws;
    float* src_proj = wsf;                                    // N*64   = 6,400,000
    float* alpha_sn = src_proj + (size_t)N_NODES * 64;        // N*4    =   400,000
    float* alpha_dn = alpha_sn + (size_t)N_NODES * 4;         // N*4    =   400,000
    float* rec_w    = alpha_dn + (size_t)N_NODES * 4;         // E*4    = 6,400,000 (16B aligned)
    int*   rec_src  = (int*)(rec_w + (size_t)N_EDGES * 4);    // E      = 1,600,000
    int*   cnt      = rec_src + N_EDGES;                      // N
    int*   row_start= cnt + N_NODES;                          // N+1 (pad to N+4)
    int*   cursor   = row_start + N_NODES + 4;                // N
    float* V        = (float*)(cursor + N_NODES);             // 68
    // total ~61.6 MB

    hipMemsetAsync(cnt, 0, (size_t)N_NODES * sizeof(int), stream);

    k_node_proj<<<N_NODES / 32, 256, 0, stream>>>(x, Wsrc, bsrc, Wdst, bdst,
                                                  att_s, att_d, src_proj,
                                                  alpha_sn, alpha_dn);
    k_prep<<<1, 64, 0, stream>>>(We, be, att_e, V);
    k_hist<<<N_EDGES / 256, 256, 0, stream>>>(ei, cnt);
    k_scan<<<1, SCAN_T, 0, stream>>>(cnt, row_start, cursor);
    k_fill<<<N_EDGES / 256, 256, 0, stream>>>(ei, ea, V, alpha_sn, alpha_dn,
                                              cursor, rec_src, (float4*)rec_w);
    k_gather<<<(N_NODES * 64) / 256, 256, 0, stream>>>(row_start, rec_src,
                                                       rec_w, src_proj, out);
}

// Round 3
// 587.296 us; speedup vs baseline: 1.6585x; 1.3698x over previous
//
#include <hip/hip_runtime.h>

// EdgeGATConv on MI355X — R3: parallel 3-phase scan (R2's single-block scan was 235us).
// Pipeline:
//   k_node_proj : src_proj = x@W_src+b (stored); alpha_sn/alpha_dn = attention dots
//   k_prep      : V[k,h] = reduce(W_edge, att_edge), + reduced bias
//   k_hist      : cnt[dst]++
//   k_scan_part / k_scan_top / k_scan_down : exclusive scan -> row_start, cursor
//   k_fill      : per edge: w = exp(leaky(asn[src]+adn[dst]+ea@V+be));
//                 slot = cursor[dst]++; rec_src[slot]=src; rec_w[slot]=w (float4)
//   k_gather    : wave per node: acc[l] += w[h]*src_proj[src][l]; denom += w[h];
//                 out[n][l] = acc/(denom+1e-16)

#define N_NODES 100000
#define N_EDGES 1600000
#define SCAN_B 1024
#define SCAN_NBLK ((N_NODES + SCAN_B - 1) / SCAN_B)   // 98

__global__ __launch_bounds__(256) void k_node_proj(
    const float* __restrict__ x, const float* __restrict__ Wsrc,
    const float* __restrict__ bsrc, const float* __restrict__ Wdst,
    const float* __restrict__ bdst, const float* __restrict__ att_src,
    const float* __restrict__ att_dst, float* __restrict__ src_proj,
    float* __restrict__ alpha_sn, float* __restrict__ alpha_dn)
{
    __shared__ float xs[32 * 128];              // 16 KB: 32 node rows
    const int tid = threadIdx.x;
    const int nbase = blockIdx.x * 32;

    const float4* xsrc = (const float4*)(x + (size_t)nbase * 128);
    float4* xd = (float4*)xs;
#pragma unroll
    for (int i = 0; i < 4; ++i)
        xd[tid + i * 256] = xsrc[tid + i * 256];
    __syncthreads();

    const int col = tid & 63;
    const int g = tid >> 6;                     // wave id 0..3, nodes g*8..g*8+7

    float accS[8], accD[8];
#pragma unroll
    for (int i = 0; i < 8; ++i) { accS[i] = 0.f; accD[i] = 0.f; }

    for (int k4 = 0; k4 < 128; k4 += 4) {
        float4 xv[8];
#pragma unroll
        for (int i = 0; i < 8; ++i)
            xv[i] = *(const float4*)&xs[(g * 8 + i) * 128 + k4];
#pragma unroll
        for (int kk = 0; kk < 4; ++kk) {
            float wsv = Wsrc[(k4 + kk) * 64 + col];
            float wdv = Wdst[(k4 + kk) * 64 + col];
#pragma unroll
            for (int i = 0; i < 8; ++i) {
                float xvk = ((const float*)&xv[i])[kk];
                accS[i] = fmaf(xvk, wsv, accS[i]);
                accD[i] = fmaf(xvk, wdv, accD[i]);
            }
        }
    }

    const float bs = bsrc[col], bd = bdst[col];
    const float as_ = att_src[col], ad_ = att_dst[col];
    const int h = col >> 4;
#pragma unroll
    for (int i = 0; i < 8; ++i) {
        const int n = nbase + g * 8 + i;
        float vS = accS[i] + bs;
        float vD = accD[i] + bd;
        src_proj[(size_t)n * 64 + col] = vS;
        float t1 = vS * as_;
        float t2 = vD * ad_;
#pragma unroll
        for (int off = 8; off >= 1; off >>= 1) {
            t1 += __shfl_xor(t1, off, 16);
            t2 += __shfl_xor(t2, off, 16);
        }
        if ((col & 15) == 0) {
            alpha_sn[n * 4 + h] = t1;
            alpha_dn[n * 4 + h] = t2;
        }
    }
}

__global__ void k_prep(const float* __restrict__ We, const float* __restrict__ be,
                       const float* __restrict__ att_e, float* __restrict__ V)
{
    const int t = threadIdx.x;            // 64 threads
    const int k = t >> 2, h = t & 3;
    float acc = 0.f;
    for (int c = 0; c < 16; ++c)
        acc += We[k * 64 + h * 16 + c] * att_e[h * 16 + c];
    V[k * 4 + h] = acc;
    if (t < 4) {
        float b = 0.f;
        for (int c = 0; c < 16; ++c)
            b += be[t * 16 + c] * att_e[t * 16 + c];
        V[64 + t] = b;
    }
}

__global__ __launch_bounds__(256) void k_hist(const int* __restrict__ ei,
                                               int* __restrict__ cnt)
{
    const int e = blockIdx.x * 256 + threadIdx.x;
    if (e >= N_EDGES) return;
    atomicAdd(&cnt[ei[N_EDGES + e]], 1);
}

// Phase 1: per-block sums of cnt (1024 elems / block, 256 thr x 4)
__global__ __launch_bounds__(256) void k_scan_part(const int* __restrict__ cnt,
                                                    int* __restrict__ partial)
{
    __shared__ int red[4];
    const int t = threadIdx.x;
    const int base = blockIdx.x * SCAN_B + t * 4;
    int s = 0;
#pragma unroll
    for (int i = 0; i < 4; ++i) {
        const int idx = base + i;
        if (idx < N_NODES) s += cnt[idx];
    }
#pragma unroll
    for (int off = 32; off >= 1; off >>= 1)
        s += __shfl_xor(s, off, 64);
    if ((t & 63) == 0) red[t >> 6] = s;
    __syncthreads();
    if (t == 0)
        partial[blockIdx.x] = red[0] + red[1] + red[2] + red[3];
}

// Phase 2: exclusive scan of 98 partials (single tiny block)
__global__ __launch_bounds__(128) void k_scan_top(int* __restrict__ partial)
{
    __shared__ int sums[128];
    const int t = threadIdx.x;
    sums[t] = (t < SCAN_NBLK) ? partial[t] : 0;
    __syncthreads();
#pragma unroll
    for (int off = 1; off < 128; off <<= 1) {
        int v = (t >= off) ? sums[t - off] : 0;
        __syncthreads();
        sums[t] += v;
        __syncthreads();
    }
    if (t < SCAN_NBLK) partial[t] = (t == 0) ? 0 : sums[t - 1];
}

// Phase 3: per-block exclusive scan + global offset -> row_start, cursor
__global__ __launch_bounds__(256) void k_scan_down(
    const int* __restrict__ cnt, const int* __restrict__ partial,
    int* __restrict__ row_start, int* __restrict__ cursor)
{
    __shared__ int tsum[256];
    const int t = threadIdx.x;
    const int base = blockIdx.x * SCAN_B + t * 4;
    int c[4];
#pragma unroll
    for (int i = 0; i < 4; ++i) {
        const int idx = base + i;
        c[i] = (idx < N_NODES) ? cnt[idx] : 0;
    }
    const int tot = c[0] + c[1] + c[2] + c[3];
    tsum[t] = tot;
    __syncthreads();
#pragma unroll
    for (int off = 1; off < 256; off <<= 1) {
        int v = (t >= off) ? tsum[t - off] : 0;
        __syncthreads();
        tsum[t] += v;
        __syncthreads();
    }
    int run = partial[blockIdx.x] + ((t == 0) ? 0 : tsum[t - 1]);
#pragma unroll
    for (int i = 0; i < 4; ++i) {
        const int idx = base + i;
        if (idx < N_NODES) {
            row_start[idx] = run;
            cursor[idx] = run;
        }
        run += c[i];
    }
    if (blockIdx.x == 0 && t == 0)
        row_start[N_NODES] = N_EDGES;
}

__global__ __launch_bounds__(256) void k_fill(
    const int* __restrict__ ei, const float* __restrict__ ea,
    const float* __restrict__ V, const float* __restrict__ alpha_sn,
    const float* __restrict__ alpha_dn, int* __restrict__ cursor,
    int* __restrict__ rec_src, float4* __restrict__ rec_w)
{
    __shared__ float Vs[68];
    if (threadIdx.x < 68) Vs[threadIdx.x] = V[threadIdx.x];
    __syncthreads();

    const int e = blockIdx.x * 256 + threadIdx.x;
    if (e >= N_EDGES) return;
    const int src = ei[e];
    const int dst = ei[N_EDGES + e];

    const float4* ea4 = (const float4*)(ea + (size_t)e * 16);
    float ek[16];
    {
        float4 c0 = ea4[0], c1 = ea4[1], c2 = ea4[2], c3 = ea4[3];
        ek[0]=c0.x; ek[1]=c0.y; ek[2]=c0.z; ek[3]=c0.w;
        ek[4]=c1.x; ek[5]=c1.y; ek[6]=c1.z; ek[7]=c1.w;
        ek[8]=c2.x; ek[9]=c2.y; ek[10]=c2.z; ek[11]=c2.w;
        ek[12]=c3.x; ek[13]=c3.y; ek[14]=c3.z; ek[15]=c3.w;
    }
    float a[4] = {Vs[64], Vs[65], Vs[66], Vs[67]};
#pragma unroll
    for (int k = 0; k < 16; ++k) {
#pragma unroll
        for (int h = 0; h < 4; ++h)
            a[h] = fmaf(ek[k], Vs[k * 4 + h], a[h]);
    }

    const float4 asn = *(const float4*)(alpha_sn + (size_t)src * 4);
    const float4 adn = *(const float4*)(alpha_dn + (size_t)dst * 4);
    float a0 = a[0] + asn.x + adn.x;
    float a1 = a[1] + asn.y + adn.y;
    float a2 = a[2] + asn.z + adn.z;
    float a3 = a[3] + asn.w + adn.w;
    a0 = (a0 >= 0.f) ? a0 : 0.2f * a0;
    a1 = (a1 >= 0.f) ? a1 : 0.2f * a1;
    a2 = (a2 >= 0.f) ? a2 : 0.2f * a2;
    a3 = (a3 >= 0.f) ? a3 : 0.2f * a3;

    const int slot = atomicAdd(&cursor[dst], 1);
    rec_src[slot] = src;
    rec_w[slot] = make_float4(__expf(a0), __expf(a1), __expf(a2), __expf(a3));
}

__global__ __launch_bounds__(256) void k_gather(
    const int* __restrict__ row_start, const int* __restrict__ rec_src,
    const float* __restrict__ rec_w, const float* __restrict__ src_proj,
    float* __restrict__ out)
{
    const int lane = threadIdx.x & 63;
    const int node = (blockIdx.x * 256 + threadIdx.x) >> 6;
    const int h = lane >> 4;
    const int base = row_start[node];
    const int end = row_start[node + 1];

    float acc = 0.f, denom = 0.f;
    for (int j = base; j < end; ++j) {
        const int src = rec_src[j];                       // wave-uniform load
        const float wv = rec_w[(size_t)j * 4 + h];        // 4 distinct addrs
        const float v = src_proj[(size_t)src * 64 + lane];// 256B coalesced
        denom += wv;
        acc = fmaf(wv, v, acc);
    }
    out[(size_t)node * 64 + lane] = acc / (denom + 1e-16f);
}

extern "C" void kernel_launch(void* const* d_in, const int* in_sizes, int n_in,
                              void* d_out, int out_size, void* d_ws, size_t ws_size,
                              hipStream_t stream) {
    const float* x     = (const float*)d_in[0];
    const int*   ei    = (const int*)d_in[1];
    const float* ea    = (const float*)d_in[2];
    const float* Wsrc  = (const float*)d_in[3];
    const float* bsrc  = (const float*)d_in[4];
    const float* Wdst  = (const float*)d_in[5];
    const float* bdst  = (const float*)d_in[6];
    const float* We    = (const float*)d_in[7];
    const float* be    = (const float*)d_in[8];
    const float* att_s = (const float*)d_in[9];
    const float* att_d = (const float*)d_in[10];
    const float* att_e = (const float*)d_in[11];
    float* out = (float*)d_out;

    // workspace layout (4-byte units); all float4 arrays 16B-aligned
    float* wsf      = (float*)d_ws;
    float* src_proj = wsf;                                    // N*64   = 6,400,000
    float* alpha_sn = src_proj + (size_t)N_NODES * 64;        // N*4
    float* alpha_dn = alpha_sn + (size_t)N_NODES * 4;         // N*4
    float* rec_w    = alpha_dn + (size_t)N_NODES * 4;         // E*4 (16B aligned)
    int*   rec_src  = (int*)(rec_w + (size_t)N_EDGES * 4);    // E
    int*   cnt      = rec_src + N_EDGES;                      // N
    int*   row_start= cnt + N_NODES;                          // N+1 (pad to N+4)
    int*   cursor   = row_start + N_NODES + 4;                // N
    int*   partial  = cursor + N_NODES;                       // 128
    float* V        = (float*)(partial + 128);                // 68

    hipMemsetAsync(cnt, 0, (size_t)N_NODES * sizeof(int), stream);

    k_node_proj<<<N_NODES / 32, 256, 0, stream>>>(x, Wsrc, bsrc, Wdst, bdst,
                                                  att_s, att_d, src_proj,
                                                  alpha_sn, alpha_dn);
    k_prep<<<1, 64, 0, stream>>>(We, be, att_e, V);
    k_hist<<<N_EDGES / 256, 256, 0, stream>>>(ei, cnt);
    k_scan_part<<<SCAN_NBLK, 256, 0, stream>>>(cnt, partial);
    k_scan_top<<<1, 128, 0, stream>>>(partial);
    k_scan_down<<<SCAN_NBLK, 256, 0, stream>>>(cnt, partial, row_start, cursor);
    k_fill<<<N_EDGES / 256, 256, 0, stream>>>(ei, ea, V, alpha_sn, alpha_dn,
                                              cursor, rec_src, (float4*)rec_w);
    k_gather<<<(N_NODES * 64) / 256, 256, 0, stream>>>(row_start, rec_src,
                                                       rec_w, src_proj, out);
}

// Round 4
// 484.896 us; speedup vs baseline: 2.0088x; 1.2112x over previous
//
#include <hip/hip_runtime.h>

// EdgeGATConv on MI355X — R4: bf16 messages + fused 16B edge records + unrolled gather.
// Pipeline:
//   k_node_proj : src_proj_bf16 = bf16(x@W_src+b); alpha_sn/alpha_dn fp32 attention dots
//   k_prep      : V[k,h] = reduce(W_edge, att_edge), + reduced bias
//   k_hist      : cnt[dst]++
//   k_scan_*    : parallel exclusive scan -> row_start, cursor
//   k_fill      : per edge: w = exp(leaky(...)); rec[slot] = {src, bf16 w x4} one dwordx4
//   k_gather    : wave per node, unroll-4: acc += w[h]*v; out = acc/(denom+1e-16)

#define N_NODES 100000
#define N_EDGES 1600000
#define SCAN_B 1024
#define SCAN_NBLK ((N_NODES + SCAN_B - 1) / SCAN_B)   // 98

// float -> bf16 bits, round-to-nearest-even (no NaN inputs here)
static __device__ __forceinline__ unsigned int f2bf(float f) {
    unsigned int u = __float_as_uint(f);
    return (u + 0x7fffu + ((u >> 16) & 1u)) >> 16;
}
static __device__ __forceinline__ float bf2f(unsigned int bits16) {
    return __uint_as_float(bits16 << 16);
}

__global__ __launch_bounds__(256) void k_node_proj(
    const float* __restrict__ x, const float* __restrict__ Wsrc,
    const float* __restrict__ bsrc, const float* __restrict__ Wdst,
    const float* __restrict__ bdst, const float* __restrict__ att_src,
    const float* __restrict__ att_dst, unsigned short* __restrict__ spbf,
    float* __restrict__ alpha_sn, float* __restrict__ alpha_dn)
{
    __shared__ float xs[32 * 128];              // 16 KB: 32 node rows
    const int tid = threadIdx.x;
    const int nbase = blockIdx.x * 32;

    const float4* xsrc = (const float4*)(x + (size_t)nbase * 128);
    float4* xd = (float4*)xs;
#pragma unroll
    for (int i = 0; i < 4; ++i)
        xd[tid + i * 256] = xsrc[tid + i * 256];
    __syncthreads();

    const int col = tid & 63;
    const int g = tid >> 6;                     // wave id 0..3, nodes g*8..g*8+7

    float accS[8], accD[8];
#pragma unroll
    for (int i = 0; i < 8; ++i) { accS[i] = 0.f; accD[i] = 0.f; }

    for (int k4 = 0; k4 < 128; k4 += 4) {
        float4 xv[8];
#pragma unroll
        for (int i = 0; i < 8; ++i)
            xv[i] = *(const float4*)&xs[(g * 8 + i) * 128 + k4];
#pragma unroll
        for (int kk = 0; kk < 4; ++kk) {
            float wsv = Wsrc[(k4 + kk) * 64 + col];
            float wdv = Wdst[(k4 + kk) * 64 + col];
#pragma unroll
            for (int i = 0; i < 8; ++i) {
                float xvk = ((const float*)&xv[i])[kk];
                accS[i] = fmaf(xvk, wsv, accS[i]);
                accD[i] = fmaf(xvk, wdv, accD[i]);
            }
        }
    }

    const float bs = bsrc[col], bd = bdst[col];
    const float as_ = att_src[col], ad_ = att_dst[col];
    const int h = col >> 4;
#pragma unroll
    for (int i = 0; i < 8; ++i) {
        const int n = nbase + g * 8 + i;
        float vS = accS[i] + bs;
        float vD = accD[i] + bd;
        spbf[(size_t)n * 64 + col] = (unsigned short)f2bf(vS);
        float t1 = vS * as_;
        float t2 = vD * ad_;
#pragma unroll
        for (int off = 8; off >= 1; off >>= 1) {
            t1 += __shfl_xor(t1, off, 16);
            t2 += __shfl_xor(t2, off, 16);
        }
        if ((col & 15) == 0) {
            alpha_sn[n * 4 + h] = t1;
            alpha_dn[n * 4 + h] = t2;
        }
    }
}

__global__ void k_prep(const float* __restrict__ We, const float* __restrict__ be,
                       const float* __restrict__ att_e, float* __restrict__ V)
{
    const int t = threadIdx.x;            // 64 threads
    const int k = t >> 2, h = t & 3;
    float acc = 0.f;
    for (int c = 0; c < 16; ++c)
        acc += We[k * 64 + h * 16 + c] * att_e[h * 16 + c];
    V[k * 4 + h] = acc;
    if (t < 4) {
        float b = 0.f;
        for (int c = 0; c < 16; ++c)
            b += be[t * 16 + c] * att_e[t * 16 + c];
        V[64 + t] = b;
    }
}

__global__ __launch_bounds__(256) void k_hist(const int* __restrict__ ei,
                                               int* __restrict__ cnt)
{
    const int e = blockIdx.x * 256 + threadIdx.x;
    if (e >= N_EDGES) return;
    atomicAdd(&cnt[ei[N_EDGES + e]], 1);
}

__global__ __launch_bounds__(256) void k_scan_part(const int* __restrict__ cnt,
                                                    int* __restrict__ partial)
{
    __shared__ int red[4];
    const int t = threadIdx.x;
    const int base = blockIdx.x * SCAN_B + t * 4;
    int s = 0;
#pragma unroll
    for (int i = 0; i < 4; ++i) {
        const int idx = base + i;
        if (idx < N_NODES) s += cnt[idx];
    }
#pragma unroll
    for (int off = 32; off >= 1; off >>= 1)
        s += __shfl_xor(s, off, 64);
    if ((t & 63) == 0) red[t >> 6] = s;
    __syncthreads();
    if (t == 0)
        partial[blockIdx.x] = red[0] + red[1] + red[2] + red[3];
}

__global__ __launch_bounds__(128) void k_scan_top(int* __restrict__ partial)
{
    __shared__ int sums[128];
    const int t = threadIdx.x;
    sums[t] = (t < SCAN_NBLK) ? partial[t] : 0;
    __syncthreads();
#pragma unroll
    for (int off = 1; off < 128; off <<= 1) {
        int v = (t >= off) ? sums[t - off] : 0;
        __syncthreads();
        sums[t] += v;
        __syncthreads();
    }
    if (t < SCAN_NBLK) partial[t] = (t == 0) ? 0 : sums[t - 1];
}

__global__ __launch_bounds__(256) void k_scan_down(
    const int* __restrict__ cnt, const int* __restrict__ partial,
    int* __restrict__ row_start, int* __restrict__ cursor)
{
    __shared__ int tsum[256];
    const int t = threadIdx.x;
    const int base = blockIdx.x * SCAN_B + t * 4;
    int c[4];
#pragma unroll
    for (int i = 0; i < 4; ++i) {
        const int idx = base + i;
        c[i] = (idx < N_NODES) ? cnt[idx] : 0;
    }
    const int tot = c[0] + c[1] + c[2] + c[3];
    tsum[t] = tot;
    __syncthreads();
#pragma unroll
    for (int off = 1; off < 256; off <<= 1) {
        int v = (t >= off) ? tsum[t - off] : 0;
        __syncthreads();
        tsum[t] += v;
        __syncthreads();
    }
    int run = partial[blockIdx.x] + ((t == 0) ? 0 : tsum[t - 1]);
#pragma unroll
    for (int i = 0; i < 4; ++i) {
        const int idx = base + i;
        if (idx < N_NODES) {
            row_start[idx] = run;
            cursor[idx] = run;
        }
        run += c[i];
    }
    if (blockIdx.x == 0 && t == 0)
        row_start[N_NODES] = N_EDGES;
}

__global__ __launch_bounds__(256) void k_fill(
    const int* __restrict__ ei, const float* __restrict__ ea,
    const float* __restrict__ V, const float* __restrict__ alpha_sn,
    const float* __restrict__ alpha_dn, int* __restrict__ cursor,
    int4* __restrict__ rec)
{
    __shared__ float Vs[68];
    if (threadIdx.x < 68) Vs[threadIdx.x] = V[threadIdx.x];
    __syncthreads();

    const int e = blockIdx.x * 256 + threadIdx.x;
    if (e >= N_EDGES) return;
    const int src = ei[e];
    const int dst = ei[N_EDGES + e];

    const float4* ea4 = (const float4*)(ea + (size_t)e * 16);
    float ek[16];
    {
        float4 c0 = ea4[0], c1 = ea4[1], c2 = ea4[2], c3 = ea4[3];
        ek[0]=c0.x; ek[1]=c0.y; ek[2]=c0.z; ek[3]=c0.w;
        ek[4]=c1.x; ek[5]=c1.y; ek[6]=c1.z; ek[7]=c1.w;
        ek[8]=c2.x; ek[9]=c2.y; ek[10]=c2.z; ek[11]=c2.w;
        ek[12]=c3.x; ek[13]=c3.y; ek[14]=c3.z; ek[15]=c3.w;
    }
    float a[4] = {Vs[64], Vs[65], Vs[66], Vs[67]};
#pragma unroll
    for (int k = 0; k < 16; ++k) {
#pragma unroll
        for (int h = 0; h < 4; ++h)
            a[h] = fmaf(ek[k], Vs[k * 4 + h], a[h]);
    }

    const float4 asn = *(const float4*)(alpha_sn + (size_t)src * 4);
    const float4 adn = *(const float4*)(alpha_dn + (size_t)dst * 4);
    float a0 = a[0] + asn.x + adn.x;
    float a1 = a[1] + asn.y + adn.y;
    float a2 = a[2] + asn.z + adn.z;
    float a3 = a[3] + asn.w + adn.w;
    a0 = (a0 >= 0.f) ? a0 : 0.2f * a0;
    a1 = (a1 >= 0.f) ? a1 : 0.2f * a1;
    a2 = (a2 >= 0.f) ? a2 : 0.2f * a2;
    a3 = (a3 >= 0.f) ? a3 : 0.2f * a3;

    const unsigned int w01 = f2bf(__expf(a0)) | (f2bf(__expf(a1)) << 16);
    const unsigned int w23 = f2bf(__expf(a2)) | (f2bf(__expf(a3)) << 16);

    const int slot = atomicAdd(&cursor[dst], 1);
    rec[slot] = make_int4(src, (int)w01, (int)w23, 0);
}

// one wave per node; unroll-4 over incoming edges for memory-level parallelism
__global__ __launch_bounds__(256) void k_gather(
    const int* __restrict__ row_start, const int4* __restrict__ rec,
    const unsigned short* __restrict__ spbf, float* __restrict__ out)
{
    const int lane = threadIdx.x & 63;
    const int node = (blockIdx.x * 256 + threadIdx.x) >> 6;
    const int h = lane >> 4;
    const int base = row_start[node];
    const int end = row_start[node + 1];

    float acc = 0.f, denom = 0.f;
    int j = base;
    for (; j + 4 <= end; j += 4) {
        const int4 r0 = rec[j], r1 = rec[j + 1], r2 = rec[j + 2], r3 = rec[j + 3];
        const float v0 = bf2f(spbf[((size_t)r0.x << 6) + lane]);
        const float v1 = bf2f(spbf[((size_t)r1.x << 6) + lane]);
        const float v2 = bf2f(spbf[((size_t)r2.x << 6) + lane]);
        const float v3 = bf2f(spbf[((size_t)r3.x << 6) + lane]);
#define WEXT(r) bf2f(((h & 1) ? ((unsigned int)((h < 2) ? r.y : r.z) >> 16) \
                              : ((unsigned int)((h < 2) ? r.y : r.z) & 0xffffu)))
        const float w0 = WEXT(r0), w1 = WEXT(r1), w2 = WEXT(r2), w3 = WEXT(r3);
        denom += (w0 + w1) + (w2 + w3);
        acc = fmaf(w0, v0, acc);
        acc = fmaf(w1, v1, acc);
        acc = fmaf(w2, v2, acc);
        acc = fmaf(w3, v3, acc);
    }
    for (; j < end; ++j) {
        const int4 r0 = rec[j];
        const float v0 = bf2f(spbf[((size_t)r0.x << 6) + lane]);
        const float w0 = WEXT(r0);
        denom += w0;
        acc = fmaf(w0, v0, acc);
    }
#undef WEXT
    out[(size_t)node * 64 + lane] = acc / (denom + 1e-16f);
}

extern "C" void kernel_launch(void* const* d_in, const int* in_sizes, int n_in,
                              void* d_out, int out_size, void* d_ws, size_t ws_size,
                              hipStream_t stream) {
    const float* x     = (const float*)d_in[0];
    const int*   ei    = (const int*)d_in[1];
    const float* ea    = (const float*)d_in[2];
    const float* Wsrc  = (const float*)d_in[3];
    const float* bsrc  = (const float*)d_in[4];
    const float* Wdst  = (const float*)d_in[5];
    const float* bdst  = (const float*)d_in[6];
    const float* We    = (const float*)d_in[7];
    const float* be    = (const float*)d_in[8];
    const float* att_s = (const float*)d_in[9];
    const float* att_d = (const float*)d_in[10];
    const float* att_e = (const float*)d_in[11];
    float* out = (float*)d_out;

    // workspace layout — rec first for 16B alignment; ~41.6 MB total
    int4*  rec       = (int4*)d_ws;                            // E*16B = 25.6 MB
    unsigned short* spbf = (unsigned short*)(rec + N_EDGES);   // N*64*2B = 12.8 MB
    float* alpha_sn  = (float*)(spbf + (size_t)N_NODES * 64);  // N*4 (16B-aligned)
    float* alpha_dn  = alpha_sn + (size_t)N_NODES * 4;         // N*4
    int*   cnt       = (int*)(alpha_dn + (size_t)N_NODES * 4); // N
    int*   row_start = cnt + N_NODES;                          // N+1 (pad 4)
    int*   cursor    = row_start + N_NODES + 4;                // N
    int*   partial   = cursor + N_NODES;                       // 128
    float* V         = (float*)(partial + 128);                // 68

    hipMemsetAsync(cnt, 0, (size_t)N_NODES * sizeof(int), stream);

    k_node_proj<<<N_NODES / 32, 256, 0, stream>>>(x, Wsrc, bsrc, Wdst, bdst,
                                                  att_s, att_d, spbf,
                                                  alpha_sn, alpha_dn);
    k_prep<<<1, 64, 0, stream>>>(We, be, att_e, V);
    k_hist<<<N_EDGES / 256, 256, 0, stream>>>(ei, cnt);
    k_scan_part<<<SCAN_NBLK, 256, 0, stream>>>(cnt, partial);
    k_scan_top<<<1, 128, 0, stream>>>(partial);
    k_scan_down<<<SCAN_NBLK, 256, 0, stream>>>(cnt, partial, row_start, cursor);
    k_fill<<<N_EDGES / 256, 256, 0, stream>>>(ei, ea, V, alpha_sn, alpha_dn,
                                              cursor, rec);
    k_gather<<<(N_NODES + 3) / 4, 256, 0, stream>>>(row_start, rec, spbf, out);
}